// Round 3
// baseline (318.353 us; speedup 1.0000x reference)
//
#include <hip/hip_runtime.h>
#include <hip/hip_bf16.h>
#include <cstdint>

#define H 128
#define EPS 1e-5f
#define CAP 32  // bucket capacity per node (Poisson(6): P(deg>32) ~ 1e-14/node)
#define NB 16   // bn_acc atomic banks (blockIdx&15)

typedef unsigned int uint;
typedef unsigned short ushort;
typedef short short8 __attribute__((ext_vector_type(8)));   // 8 bf16 (4 VGPRs)
typedef float f32x4 __attribute__((ext_vector_type(4)));    // MFMA C/D frag

// bf16 helpers (RNE pack, finite inputs)
__device__ __forceinline__ ushort f2bf(float f) {
  uint u = __float_as_uint(f);
  u += 0x7fffu + ((u >> 16) & 1u);
  return (ushort)(u >> 16);
}
__device__ __forceinline__ float bflo(uint v) { return __uint_as_float(v << 16); }
__device__ __forceinline__ float bfhi(uint v) { return __uint_as_float(v & 0xffff0000u); }

// Fused pre-dispatch: [0,ZB) zero cnt + bn banks (+int64 detect in block 0)
// | [ZB,ZB+EB) embed | rest: weight pre-swizzle.
__global__ __launch_bounds__(256) void k_init(const void* __restrict__ ei, int N,
                                              uint* __restrict__ cnt, int* __restrict__ flag,
                                              const float* __restrict__ F, const float* __restrict__ embW,
                                              const float* __restrict__ embB,
                                              ushort* __restrict__ bufA, ushort* __restrict__ bufB,
                                              const float* __restrict__ Wself, const float* __restrict__ Wneigh,
                                              const float* __restrict__ W1,
                                              ushort* __restrict__ Wsw, ushort* __restrict__ W1sw,
                                              float* __restrict__ bn_all,
                                              int ZB, int EB) {
  __shared__ float sW[12 * 128];
  __shared__ float sF[256 * 12];
  int b = blockIdx.x, t = threadIdx.x;
  if (b < ZB) {  // ---- zero cnt + per-layer bn banks + detect ----
    int i = b * 256 + t;
    if (i < N) cnt[i] = 0u;
    if (b == 0) {
      for (int j = t; j < NB * 256 * 3; j += 256) bn_all[j] = 0.f;
      if (t == 0) {
        const long long* p = (const long long*)ei;
        int ok = 1;
        for (int j = 0; j < 16; ++j) {
          long long s = p[j];
          if (s < 0 || s >= (long long)N) ok = 0;
        }
        *flag = ok;
      }
    }
    return;
  }
  if (b < ZB + EB) {  // ---- embedding: 256 rows/block ----
    int blk = b - ZB;
    for (int i = t; i < 12 * 128; i += 256) sW[i] = embW[i];
    int row0 = blk * 256;
    int nrows = min(256, N - row0);
    for (int i = t; i < nrows * 12; i += 256) sF[i] = F[(size_t)row0 * 12 + i];
    __syncthreads();
    int col = t & 127, half = t >> 7;
    float bias = embB[col];
    int rlo = half * 128, rhi = min(nrows, rlo + 128);
    for (int r = rlo; r < rhi; ++r) {
      float acc = bias;
#pragma unroll
      for (int k = 0; k < 12; ++k) acc = fmaf(sF[r * 12 + k], sW[k * 128 + col], acc);
      bufA[(size_t)(row0 + r) * H + col] = f2bf(acc);
    }
    if (blk == 0 && t < 128) {  // zero row N (dummy-slot target) in both buffers
      bufA[(size_t)N * H + t] = 0;
      bufB[(size_t)N * H + t] = 0;
    }
    return;
  }
  // ---- weight pre-swizzle into MFMA B-fragment order ----
  int e = (b - ZB - EB) * 256 + t;
  if (e < 3 * 4096) {
    int l = e >> 12, r = e & 4095;
    int kt = r >> 9, nt = (r >> 6) & 7, lane = r & 63;
    int quad = lane >> 4, l16 = lane & 15;
    int n = nt * 16 + l16;
    ushort* dst = Wsw + ((size_t)l * 4096 + (kt * 8 + nt) * 64 + lane) * 8;
#pragma unroll
    for (int j = 0; j < 8; ++j) {
      int k = kt * 32 + quad * 8 + j;
      float v = (k < 128) ? Wself[(size_t)l * H * H + (size_t)k * H + n]
                          : Wneigh[(size_t)l * H * H + (size_t)(k - 128) * H + n];
      dst[j] = f2bf(v);
    }
  } else if (e < 3 * 4096 + 1024) {
    int r = e - 3 * 4096;
    int kt = r >> 8, nt = (r >> 6) & 3, lane = r & 63;
    int quad = lane >> 4, l16 = lane & 15;
    int n = nt * 16 + l16;
    ushort* dst = W1sw + ((size_t)((kt * 4 + nt) * 64 + lane)) * 8;
#pragma unroll
    for (int j = 0; j < 8; ++j) {
      int k = kt * 32 + quad * 8 + j;
      dst[j] = f2bf(W1[(size_t)k * 64 + n]);
    }
  }
}

// Bucket-CSR fill: 2 edges/thread, vectorized 16B index loads. (R10 config.)
__global__ __launch_bounds__(256) void k_fill(const void* __restrict__ ei, uint* __restrict__ cnt,
                                              uint* __restrict__ csr, int E,
                                              const int* __restrict__ flag) {
  int e0 = (blockIdx.x * 256 + threadIdx.x) * 2;  // even -> 16B-aligned pair
  if (e0 >= E) return;
  int is64 = *flag;
  int s0, s1 = -1, d0, d1 = -1;
  bool two = (e0 + 1 < E);
  if (is64) {
    const unsigned long long* p = (const unsigned long long*)ei;
    if (two) {
      ulong2 sv = *(const ulong2*)(p + e0);
      ulong2 dv = *(const ulong2*)(p + E + e0);
      s0 = (int)sv.x; s1 = (int)sv.y; d0 = (int)dv.x; d1 = (int)dv.y;
    } else {
      s0 = (int)p[e0]; d0 = (int)p[E + e0];
    }
  } else {
    const int* p = (const int*)ei;
    if (two) {
      int2 sv = *(const int2*)(p + e0);
      int2 dv = *(const int2*)(p + E + e0);
      s0 = sv.x; s1 = sv.y; d0 = dv.x; d1 = dv.y;
    } else {
      s0 = p[e0]; d0 = p[E + e0];
    }
  }
  uint p0 = atomicAdd(&cnt[d0], 1u);
  if (p0 < (uint)CAP) csr[(size_t)d0 * CAP + p0] = (uint)s0;
  if (two) {
    uint p1 = atomicAdd(&cnt[d1], 1u);
    if (p1 < (uint)CAP) csr[(size_t)d1 * CAP + p1] = (uint)s1;
  }
}

// R13: fused gather+GEMM, M-tile 64 (grid ~1563 = 6.1 blocks/CU; R12's 128-tile
// grid was 3.05/CU and OccupancyPercent=24% showed the grid itself capped the
// gather's latency-hiding). LDS 17.4KB, acc[8] (~48 VGPR) -> launch_bounds
// (256,6). Phase A: the first 8-slot chunk (deg<=8 covers ~85% of Poisson(6)
// nodes) is straight-line in the unrolled 4-node loop so the compiler can
// overlap the 4 nodes' index/value loads; rare deg>8 tail stays a loop.
// Phase B: self half (global A) pre-barrier, neighbor half from swizzled LDS,
// B-fragments straight from L2. BN partials -> banked accumulators.
__global__ __launch_bounds__(256, 6) void k_gg(const ushort* __restrict__ h, ushort* __restrict__ z,
                                               const uint* __restrict__ cnt, const uint* __restrict__ csr,
                                               const ushort* __restrict__ Wsw, const float* __restrict__ bias,
                                               float* __restrict__ bn_acc, int N) {
  __shared__ char smem[17408];       // 16KB msg tile (64 rows x 256B, swizzled)
  ushort* sMsg = (ushort*)smem;      // + reused as 17.4KB BN reduction buffer
  int tid = threadIdx.x;
  int wave = tid >> 6, lane = tid & 63, quad = lane >> 4, l16 = lane & 15;
  int row0 = blockIdx.x * 64;

  // ---- phase A: gather 64 msg rows -> LDS (16-lane group per node, 4 nodes/group) ----
  {
    const uint4* hu = (const uint4*)h;  // h row = 16 uint4
#pragma unroll
    for (int p = 0; p < 4; ++p) {
      int nl = p * 16 + wave * 4 + quad;  // local row 0..63
      int n = row0 + nl;
      uint rawc = (n < N) ? cnt[n] : 0u;
      uint deg = min(rawc, (uint)CAP);
      const uint* row = csr + (size_t)min(n, N - 1) * CAP;
      float a0 = 0.f, a1 = 0.f, a2 = 0.f, a3 = 0.f, a4 = 0.f, a5 = 0.f, a6 = 0.f, a7 = 0.f;
      // chunk 0 (straight-line; deg==0 lanes read zero row N)
      {
        uint4 r0 = *(const uint4*)(row);
        uint4 r1 = *(const uint4*)(row + 4);
        uint raw[8] = {r0.x, r0.y, r0.z, r0.w, r1.x, r1.y, r1.z, r1.w};
        uint idx[8];
#pragma unroll
        for (int j = 0; j < 8; ++j) idx[j] = ((uint)j < deg) ? raw[j] : (uint)N;
        uint4 v[8];
#pragma unroll
        for (int j = 0; j < 8; ++j) v[j] = hu[(size_t)idx[j] * 16 + l16];
#pragma unroll
        for (int j = 0; j < 8; ++j) {
          a0 += bflo(v[j].x); a1 += bfhi(v[j].x);
          a2 += bflo(v[j].y); a3 += bfhi(v[j].y);
          a4 += bflo(v[j].z); a5 += bfhi(v[j].z);
          a6 += bflo(v[j].w); a7 += bfhi(v[j].w);
        }
      }
      if (deg > 8) {  // rare tail (P ~ 0.15 at Poisson(6))
        for (uint k = 8; k < deg; k += 8) {
          uint4 r0 = *(const uint4*)(row + k);
          uint4 r1 = *(const uint4*)(row + k + 4);
          uint raw[8] = {r0.x, r0.y, r0.z, r0.w, r1.x, r1.y, r1.z, r1.w};
          uint idx[8];
#pragma unroll
          for (int j = 0; j < 8; ++j) idx[j] = (k + j < deg) ? raw[j] : (uint)N;
          uint4 v[8];
#pragma unroll
          for (int j = 0; j < 8; ++j) v[j] = hu[(size_t)idx[j] * 16 + l16];
#pragma unroll
          for (int j = 0; j < 8; ++j) {
            a0 += bflo(v[j].x); a1 += bfhi(v[j].x);
            a2 += bflo(v[j].y); a3 += bfhi(v[j].y);
            a4 += bflo(v[j].z); a5 += bfhi(v[j].z);
            a6 += bflo(v[j].w); a7 += bfhi(v[j].w);
          }
        }
      }
      float inv = 1.0f / (float)max(rawc, 1u);
      uint4 o;
      o.x = (uint)f2bf(a0 * inv) | ((uint)f2bf(a1 * inv) << 16);
      o.y = (uint)f2bf(a2 * inv) | ((uint)f2bf(a3 * inv) << 16);
      o.z = (uint)f2bf(a4 * inv) | ((uint)f2bf(a5 * inv) << 16);
      o.w = (uint)f2bf(a6 * inv) | ((uint)f2bf(a7 * inv) << 16);
      int off = nl * 256 + ((l16 * 16) ^ ((nl & 7) << 4));  // swizzled 16B slot
      *(uint4*)(smem + off) = o;
    }
  }

  // ---- phase B: MFMA (wave owns 16 rows) ----
  int wrow0 = row0 + wave * 16;
  f32x4 acc[8];
#pragma unroll
  for (int nt = 0; nt < 8; ++nt) acc[nt] = (f32x4){0.f, 0.f, 0.f, 0.f};
  short8 zf8 = {0, 0, 0, 0, 0, 0, 0, 0};
  const short8* Bp = (const short8*)Wsw;  // B-frags from L2: (kt*8+nt)*64+lane

  // self half (K 0..127, A = h from global) -- no msg dependency, pre-barrier
#pragma unroll
  for (int kt = 0; kt < 4; ++kt) {
    int colb = kt * 32 + quad * 8;
    int row = wrow0 + l16;
    short8 a = (row < N) ? *(const short8*)(h + (size_t)row * H + colb) : zf8;
#pragma unroll
    for (int nt = 0; nt < 8; ++nt) {
      short8 bfr = Bp[(kt * 8 + nt) * 64 + lane];
      acc[nt] = __builtin_amdgcn_mfma_f32_16x16x32_bf16(a, bfr, acc[nt], 0, 0, 0);
    }
  }
  __syncthreads();  // msg tile complete
  // neighbor half (K 128..255, A = msg from LDS)
#pragma unroll
  for (int kt = 4; kt < 8; ++kt) {
    int cb = (kt - 4) * 64 + quad * 16;  // byte col base within row
    int rl = wave * 16 + l16;            // rl&7 == l16&7
    short8 a = *(const short8*)(smem + rl * 256 + (cb ^ ((l16 & 7) << 4)));
#pragma unroll
    for (int nt = 0; nt < 8; ++nt) {
      short8 bfr = Bp[(kt * 8 + nt) * 64 + lane];
      acc[nt] = __builtin_amdgcn_mfma_f32_16x16x32_bf16(a, bfr, acc[nt], 0, 0, 0);
    }
  }

  // ---- epilogue: bias, z-write (bf16), fused BN partial sums ----
  float bs[8];
#pragma unroll
  for (int nt = 0; nt < 8; ++nt) bs[nt] = bias[nt * 16 + l16];
  float ps[8], pq[8];
#pragma unroll
  for (int nt = 0; nt < 8; ++nt) { ps[nt] = 0.f; pq[nt] = 0.f; }
#pragma unroll
  for (int nt = 0; nt < 8; ++nt) {
    int col = nt * 16 + l16;
#pragma unroll
    for (int r = 0; r < 4; ++r) {
      int row = wrow0 + quad * 4 + r;  // C/D: row=quad*4+reg
      if (row < N) {
        float v = acc[nt][r] + bs[nt];
        z[(size_t)row * H + col] = f2bf(v);
        ps[nt] += v; pq[nt] += v * v;
      }
    }
  }
  __syncthreads();  // sMsg dead; alias reduction buffer over it (17.4KB)
  float* red = (float*)smem;  // [16 wq][8 nt] stride 17 + l16 ; sumsq at +2176
  int wq = wave * 4 + quad;
#pragma unroll
  for (int nt = 0; nt < 8; ++nt) {
    red[(wq * 8 + nt) * 17 + l16] = ps[nt];
    red[2176 + (wq * 8 + nt) * 17 + l16] = pq[nt];
  }
  __syncthreads();
  if (tid < 128) {
    int nt = tid >> 4, lc = tid & 15;
    float s = 0.f, q = 0.f;
#pragma unroll
    for (int w2i = 0; w2i < 16; ++w2i) {
      s += red[(w2i * 8 + nt) * 17 + lc];
      q += red[2176 + (w2i * 8 + nt) * 17 + lc];
    }
    float* bank = bn_acc + (size_t)(blockIdx.x & (NB - 1)) * 256;
    atomicAdd(&bank[tid], s);
    atomicAdd(&bank[128 + tid], q);
  }
}

// z = relu(z*scale+shift) (+ hprev), bf16 in place, 8 elems/thread (uint4).
// BN finalize inlined (sums NB atomic banks). n4 = N*16 uint4 elements.
__global__ __launch_bounds__(256) void k_norm(uint4* __restrict__ z, const uint4* __restrict__ hprev,
                                              const float* __restrict__ bn_acc,
                                              const float* __restrict__ gamma,
                                              const float* __restrict__ beta,
                                              int residual, int n4, float invN) {
  __shared__ float ssc[128], ssh[128];
  int t = threadIdx.x;
  if (t < 128) {
    float s = 0.f, q = 0.f;
#pragma unroll
    for (int b = 0; b < NB; ++b) {
      s += bn_acc[b * 256 + t];
      q += bn_acc[b * 256 + 128 + t];
    }
    float mu = s * invN;
    float var = fmaxf(q * invN - mu * mu, 0.f);
    float sc = gamma[t] * rsqrtf(var + EPS);
    ssc[t] = sc;
    ssh[t] = beta[t] - mu * sc;
  }
  __syncthreads();
  int idx = blockIdx.x * 256 + t;
  if (idx >= n4) return;
  int j = (idx & 15) * 8;  // cols j..j+7
  uint4 v = z[idx];
  float x0 = fmaxf(fmaf(bflo(v.x), ssc[j + 0], ssh[j + 0]), 0.f);
  float x1 = fmaxf(fmaf(bfhi(v.x), ssc[j + 1], ssh[j + 1]), 0.f);
  float x2 = fmaxf(fmaf(bflo(v.y), ssc[j + 2], ssh[j + 2]), 0.f);
  float x3 = fmaxf(fmaf(bfhi(v.y), ssc[j + 3], ssh[j + 3]), 0.f);
  float x4 = fmaxf(fmaf(bflo(v.z), ssc[j + 4], ssh[j + 4]), 0.f);
  float x5 = fmaxf(fmaf(bfhi(v.z), ssc[j + 5], ssh[j + 5]), 0.f);
  float x6 = fmaxf(fmaf(bflo(v.w), ssc[j + 6], ssh[j + 6]), 0.f);
  float x7 = fmaxf(fmaf(bfhi(v.w), ssc[j + 7], ssh[j + 7]), 0.f);
  if (residual) {
    uint4 r = hprev[idx];
    x0 += bflo(r.x); x1 += bfhi(r.x); x2 += bflo(r.y); x3 += bfhi(r.y);
    x4 += bflo(r.z); x5 += bfhi(r.z); x6 += bflo(r.w); x7 += bfhi(r.w);
  }
  uint4 o;
  o.x = (uint)f2bf(x0) | ((uint)f2bf(x1) << 16);
  o.y = (uint)f2bf(x2) | ((uint)f2bf(x3) << 16);
  o.z = (uint)f2bf(x4) | ((uint)f2bf(x5) << 16);
  o.w = (uint)f2bf(x6) | ((uint)f2bf(x7) << 16);
  z[idx] = o;
}

// Final layer: fused BN-normalize+relu+residual -> MLP head.
__global__ __launch_bounds__(256) void k_head(const ushort* __restrict__ z, const ushort* __restrict__ hprev,
                                              const float* __restrict__ bn_acc,
                                              const float* __restrict__ gamma,
                                              const float* __restrict__ beta, float invN,
                                              const ushort* __restrict__ W1sw,
                                              const float* __restrict__ b1, const float* __restrict__ W2,
                                              const float* __restrict__ b2, float* __restrict__ out, int N) {
  __shared__ float ssc[128], ssh[128];
  int tid = threadIdx.x;
  if (tid < 128) {
    float s = 0.f, q = 0.f;
#pragma unroll
    for (int b = 0; b < NB; ++b) {
      s += bn_acc[b * 256 + tid];
      q += bn_acc[b * 256 + 128 + tid];
    }
    float mu = s * invN;
    float var = fmaxf(q * invN - mu * mu, 0.f);
    float sc = gamma[tid] * rsqrtf(var + EPS);
    ssc[tid] = sc;
    ssh[tid] = beta[tid] - mu * sc;
  }
  __syncthreads();
  int wave = tid >> 6, lane = tid & 63, quad = lane >> 4, l16 = lane & 15;
  int wrow0 = blockIdx.x * 64 + wave * 16;
  int am = wrow0 + l16;
  bool avalid = am < N;
  short8 af[4];
#pragma unroll
  for (int kt = 0; kt < 4; ++kt) {
    int c0 = kt * 32 + quad * 8;
    uint4 vz = avalid ? ((const uint4*)z)[(size_t)am * 16 + kt * 4 + quad] : make_uint4(0, 0, 0, 0);
    uint4 vr = avalid ? ((const uint4*)hprev)[(size_t)am * 16 + kt * 4 + quad] : make_uint4(0, 0, 0, 0);
    float x0 = fmaxf(fmaf(bflo(vz.x), ssc[c0 + 0], ssh[c0 + 0]), 0.f) + bflo(vr.x);
    float x1 = fmaxf(fmaf(bfhi(vz.x), ssc[c0 + 1], ssh[c0 + 1]), 0.f) + bfhi(vr.x);
    float x2 = fmaxf(fmaf(bflo(vz.y), ssc[c0 + 2], ssh[c0 + 2]), 0.f) + bflo(vr.y);
    float x3 = fmaxf(fmaf(bfhi(vz.y), ssc[c0 + 3], ssh[c0 + 3]), 0.f) + bfhi(vr.y);
    float x4 = fmaxf(fmaf(bflo(vz.z), ssc[c0 + 4], ssh[c0 + 4]), 0.f) + bflo(vr.z);
    float x5 = fmaxf(fmaf(bfhi(vz.z), ssc[c0 + 5], ssh[c0 + 5]), 0.f) + bfhi(vr.z);
    float x6 = fmaxf(fmaf(bflo(vz.w), ssc[c0 + 6], ssh[c0 + 6]), 0.f) + bflo(vr.w);
    float x7 = fmaxf(fmaf(bfhi(vz.w), ssc[c0 + 7], ssh[c0 + 7]), 0.f) + bfhi(vr.w);
    ushort u[8] = {f2bf(x0), f2bf(x1), f2bf(x2), f2bf(x3), f2bf(x4), f2bf(x5), f2bf(x6), f2bf(x7)};
    af[kt] = *(short8*)u;
  }
  const short8* Bp = (const short8*)W1sw;
  f32x4 acc[4];
#pragma unroll
  for (int nt = 0; nt < 4; ++nt) acc[nt] = (f32x4){0.f, 0.f, 0.f, 0.f};
#pragma unroll
  for (int kt = 0; kt < 4; ++kt) {
#pragma unroll
    for (int nt = 0; nt < 4; ++nt) {
      short8 bfr = Bp[(kt * 4 + nt) * 64 + lane];
      acc[nt] = __builtin_amdgcn_mfma_f32_16x16x32_bf16(af[kt], bfr, acc[nt], 0, 0, 0);
    }
  }
  float p0[4] = {0.f, 0.f, 0.f, 0.f}, p1[4] = {0.f, 0.f, 0.f, 0.f};
#pragma unroll
  for (int nt = 0; nt < 4; ++nt) {
    int c = nt * 16 + l16;
    float bc = b1[c], w20 = W2[c * 2], w21 = W2[c * 2 + 1];
#pragma unroll
    for (int r = 0; r < 4; ++r) {
      float v = fmaxf(acc[nt][r] + bc, 0.f);
      p0[r] = fmaf(v, w20, p0[r]);
      p1[r] = fmaf(v, w21, p1[r]);
    }
  }
#pragma unroll
  for (int m = 1; m < 16; m <<= 1) {
#pragma unroll
    for (int r = 0; r < 4; ++r) {
      p0[r] += __shfl_xor(p0[r], m);
      p1[r] += __shfl_xor(p1[r], m);
    }
  }
  if (l16 == 0) {
    float b20 = b2[0], b21 = b2[1];
#pragma unroll
    for (int r = 0; r < 4; ++r) {
      int row = wrow0 + quad * 4 + r;
      if (row < N) {
        float2 o = make_float2(p0[r] + b20, p1[r] + b21);
        *(float2*)(out + (size_t)row * 2) = o;
      }
    }
  }
}

extern "C" void kernel_launch(void* const* d_in, const int* in_sizes, int n_in,
                              void* d_out, int out_size, void* d_ws, size_t ws_size,
                              hipStream_t stream) {
  const float* features = (const float*)d_in[0];
  const void*  edges    = d_in[1];
  const float* emb_W    = (const float*)d_in[2];
  const float* emb_b    = (const float*)d_in[3];
  const float* Wself    = (const float*)d_in[4];
  const float* Wneigh   = (const float*)d_in[5];
  const float* conv_b   = (const float*)d_in[6];
  const float* bn_gamma = (const float*)d_in[7];
  const float* bn_beta  = (const float*)d_in[8];
  const float* W1       = (const float*)d_in[9];
  const float* b1       = (const float*)d_in[10];
  const float* W2       = (const float*)d_in[11];
  const float* b2       = (const float*)d_in[12];
  float* out = (float*)d_out;
  const int N = in_sizes[0] / 12;
  const int E = in_sizes[1] / 2;
  const float invN = 1.0f / (float)N;

  char* ws = (char*)d_ws;
  size_t off = 0;
  auto take = [&](size_t bytes) {
    char* p = ws + off;
    off = (off + bytes + 511) & ~(size_t)511;
    return p;
  };
  int*    flag   = (int*)take(4);
  uint*   cnt    = (uint*)take((size_t)N * 4);
  uint*   csr    = (uint*)take((size_t)N * CAP * 4);  // bucket CSR (12.8 MB)
  float*  bn_all = (float*)take(NB * 256 * 3 * 4);    // per-layer banked BN accum
  ushort* Wsw    = (ushort*)take(3 * 4096 * 8 * 2);
  ushort* W1sw   = (ushort*)take(1024 * 8 * 2);
  ushort* bufA   = (ushort*)take(((size_t)N + 1) * H * 2);  // +1 zero row
  ushort* bufB   = (ushort*)take(((size_t)N + 1) * H * 2);

  const int ZB = (N + 255) / 256;                   // zero-cnt blocks
  const int EB = (N + 255) / 256;                   // embed blocks
  const int PB = (3 * 4096 + 1024 + 255) / 256;     // prepw blocks (52)
  const int FB = (E + 511) / 512;                   // fill blocks (2 edges/thread)
  const int GB = (N + 63) / 64;                     // fused gather+gemm blocks (M-tile 64)

  k_init<<<ZB + EB + PB, 256, 0, stream>>>(edges, N, cnt, flag, features, emb_W, emb_b,
                                           bufA, bufB, Wself, Wneigh, W1, Wsw, W1sw, bn_all, ZB, EB);
  k_fill<<<FB, 256, 0, stream>>>(edges, cnt, csr, E, flag);

  ushort* hbuf = bufA;
  ushort* obuf = bufB;
  const int n4 = N * 16;
  for (int i = 0; i < 3; ++i) {
    float* bn_i = bn_all + (size_t)i * NB * 256;
    k_gg<<<GB, 256, 0, stream>>>(hbuf, obuf, cnt, csr, Wsw + (size_t)i * 4096 * 8,
                                 conv_b + (size_t)i * H, bn_i, N);
    if (i < 2) {
      k_norm<<<(n4 + 255) / 256, 256, 0, stream>>>((uint4*)obuf, (const uint4*)hbuf, bn_i,
                                                   bn_gamma + (size_t)i * H, bn_beta + (size_t)i * H,
                                                   (i > 0) ? 1 : 0, n4, invN);
      ushort* t = hbuf; hbuf = obuf; obuf = t;
    }
  }
  // layer 2: norm fused into head (z=obuf, hprev=hbuf)
  k_head<<<(N + 63) / 64, 256, 0, stream>>>(obuf, hbuf, bn_all + (size_t)2 * NB * 256,
                                            bn_gamma + 2 * H, bn_beta + 2 * H,
                                            invN, W1sw, b1, W2, b2, out, N);
}

// Round 5
// 308.722 us; speedup vs baseline: 1.0312x; 1.0312x over previous
//
#include <hip/hip_runtime.h>
#include <hip/hip_bf16.h>
#include <cstdint>

#define H 128
#define EPS 1e-5f
#define CAP 32  // bucket capacity per node (Poisson(6): P(deg>32) ~ 1e-14/node)
#define NB 16   // bn_acc atomic banks (blockIdx&15)

typedef unsigned int uint;
typedef unsigned short ushort;
typedef short short8 __attribute__((ext_vector_type(8)));   // 8 bf16 (4 VGPRs)
typedef float f32x4 __attribute__((ext_vector_type(4)));    // MFMA C/D frag

// bf16 helpers (RNE pack, finite inputs)
__device__ __forceinline__ ushort f2bf(float f) {
  uint u = __float_as_uint(f);
  u += 0x7fffu + ((u >> 16) & 1u);
  return (ushort)(u >> 16);
}
__device__ __forceinline__ float bflo(uint v) { return __uint_as_float(v << 16); }
__device__ __forceinline__ float bfhi(uint v) { return __uint_as_float(v & 0xffff0000u); }
__device__ __forceinline__ float nrm(float x, float sc, float sh) {
  return fmaxf(fmaf(x, sc, sh), 0.f);
}

// Fused pre-dispatch: [0,ZB) zero cnt + bn banks (+int64 detect in block 0)
// | [ZB,ZB+EB) embed | rest: weight pre-swizzle.
__global__ __launch_bounds__(256) void k_init(const void* __restrict__ ei, int N,
                                              uint* __restrict__ cnt, int* __restrict__ flag,
                                              const float* __restrict__ F, const float* __restrict__ embW,
                                              const float* __restrict__ embB,
                                              ushort* __restrict__ bufA, ushort* __restrict__ bufB,
                                              const float* __restrict__ Wself, const float* __restrict__ Wneigh,
                                              const float* __restrict__ W1,
                                              ushort* __restrict__ Wsw, ushort* __restrict__ W1sw,
                                              float* __restrict__ bn_all,
                                              int ZB, int EB) {
  __shared__ float sW[12 * 128];
  __shared__ float sF[256 * 12];
  int b = blockIdx.x, t = threadIdx.x;
  if (b < ZB) {  // ---- zero cnt + per-layer bn banks + detect ----
    int i = b * 256 + t;
    if (i < N) cnt[i] = 0u;
    if (b == 0) {
      for (int j = t; j < NB * 256 * 3; j += 256) bn_all[j] = 0.f;
      if (t == 0) {
        const long long* p = (const long long*)ei;
        int ok = 1;
        for (int j = 0; j < 16; ++j) {
          long long s = p[j];
          if (s < 0 || s >= (long long)N) ok = 0;
        }
        *flag = ok;
      }
    }
    return;
  }
  if (b < ZB + EB) {  // ---- embedding: 256 rows/block ----
    int blk = b - ZB;
    for (int i = t; i < 12 * 128; i += 256) sW[i] = embW[i];
    int row0 = blk * 256;
    int nrows = min(256, N - row0);
    for (int i = t; i < nrows * 12; i += 256) sF[i] = F[(size_t)row0 * 12 + i];
    __syncthreads();
    int col = t & 127, half = t >> 7;
    float bias = embB[col];
    int rlo = half * 128, rhi = min(nrows, rlo + 128);
    for (int r = rlo; r < rhi; ++r) {
      float acc = bias;
#pragma unroll
      for (int k = 0; k < 12; ++k) acc = fmaf(sF[r * 12 + k], sW[k * 128 + col], acc);
      bufA[(size_t)(row0 + r) * H + col] = f2bf(acc);
    }
    if (blk == 0 && t < 128) {  // zero row N (dummy-slot target) in both buffers
      bufA[(size_t)N * H + t] = 0;
      bufB[(size_t)N * H + t] = 0;
    }
    return;
  }
  // ---- weight pre-swizzle into MFMA B-fragment order ----
  int e = (b - ZB - EB) * 256 + t;
  if (e < 3 * 4096) {
    int l = e >> 12, r = e & 4095;
    int kt = r >> 9, nt = (r >> 6) & 7, lane = r & 63;
    int quad = lane >> 4, l16 = lane & 15;
    int n = nt * 16 + l16;
    ushort* dst = Wsw + ((size_t)l * 4096 + (kt * 8 + nt) * 64 + lane) * 8;
#pragma unroll
    for (int j = 0; j < 8; ++j) {
      int k = kt * 32 + quad * 8 + j;
      float v = (k < 128) ? Wself[(size_t)l * H * H + (size_t)k * H + n]
                          : Wneigh[(size_t)l * H * H + (size_t)(k - 128) * H + n];
      dst[j] = f2bf(v);
    }
  } else if (e < 3 * 4096 + 1024) {
    int r = e - 3 * 4096;
    int kt = r >> 8, nt = (r >> 6) & 3, lane = r & 63;
    int quad = lane >> 4, l16 = lane & 15;
    int n = nt * 16 + l16;
    ushort* dst = W1sw + ((size_t)((kt * 4 + nt) * 64 + lane)) * 8;
#pragma unroll
    for (int j = 0; j < 8; ++j) {
      int k = kt * 32 + quad * 8 + j;
      dst[j] = f2bf(W1[(size_t)k * 64 + n]);
    }
  }
}

// Bucket-CSR fill: 2 edges/thread, vectorized 16B index loads. (R10 config.)
__global__ __launch_bounds__(256) void k_fill(const void* __restrict__ ei, uint* __restrict__ cnt,
                                              uint* __restrict__ csr, int E,
                                              const int* __restrict__ flag) {
  int e0 = (blockIdx.x * 256 + threadIdx.x) * 2;  // even -> 16B-aligned pair
  if (e0 >= E) return;
  int is64 = *flag;
  int s0, s1 = -1, d0, d1 = -1;
  bool two = (e0 + 1 < E);
  if (is64) {
    const unsigned long long* p = (const unsigned long long*)ei;
    if (two) {
      ulong2 sv = *(const ulong2*)(p + e0);
      ulong2 dv = *(const ulong2*)(p + E + e0);
      s0 = (int)sv.x; s1 = (int)sv.y; d0 = (int)dv.x; d1 = (int)dv.y;
    } else {
      s0 = (int)p[e0]; d0 = (int)p[E + e0];
    }
  } else {
    const int* p = (const int*)ei;
    if (two) {
      int2 sv = *(const int2*)(p + e0);
      int2 dv = *(const int2*)(p + E + e0);
      s0 = sv.x; s1 = sv.y; d0 = dv.x; d1 = dv.y;
    } else {
      s0 = p[e0]; d0 = p[E + e0];
    }
  }
  uint p0 = atomicAdd(&cnt[d0], 1u);
  if (p0 < (uint)CAP) csr[(size_t)d0 * CAP + p0] = (uint)s0;
  if (two) {
    uint p1 = atomicAdd(&cnt[d1], 1u);
    if (p1 < (uint)CAP) csr[(size_t)d1 * CAP + p1] = (uint)s1;
  }
}

// R14 (resubmit after infra failure): fused gather+GEMM, R2-proven geometry
// (M-tile 128, 4 blocks/CU; R3's M-64 experiment REGRESSED -- gather is at
// the random-fetch fabric floor, not occupancy-limited). MODE=1 applies the
// PREVIOUS layer's BN+relu on the fly to every input row it reads
// (gather: masked fmac accumulate; self-GEMM: affine+repack), eliminating
// the layer-0 k_norm kernel and its 77MB round trip. The extra ~2 VALU
// ops/element hide under the gather's load latency (VALUBusy was 28%).
template <int MODE>
__global__ __launch_bounds__(256, 4) void k_gg(const ushort* __restrict__ h, ushort* __restrict__ z,
                                               const uint* __restrict__ cnt, const uint* __restrict__ csr,
                                               const ushort* __restrict__ Wsw, const float* __restrict__ bias,
                                               float* __restrict__ bn_acc, int N,
                                               const float* __restrict__ bn_prev,
                                               const float* __restrict__ gprev,
                                               const float* __restrict__ bprev, float invN) {
  __shared__ ushort sMsg[128 * 128];  // 32 KB msg tile, row = 256 B, swizzled
  __shared__ float ssc[128], ssh[128];  // MODE=1: prev-layer BN scale/shift
  int tid = threadIdx.x;
  int wave = tid >> 6, lane = tid & 63, quad = lane >> 4, l16 = lane & 15;
  int row0 = blockIdx.x * 128;

  if (MODE) {
    if (tid < 128) {
      float s = 0.f, q = 0.f;
#pragma unroll
      for (int b = 0; b < NB; ++b) {
        s += bn_prev[b * 256 + tid];
        q += bn_prev[b * 256 + 128 + tid];
      }
      float mu = s * invN;
      float var = fmaxf(q * invN - mu * mu, 0.f);
      float sc = gprev[tid] * rsqrtf(var + EPS);
      ssc[tid] = sc;
      ssh[tid] = bprev[tid] - mu * sc;
    }
    __syncthreads();
  }
  float sc8[8], sh8[8];  // gather columns are fixed per lane: l16*8 .. +7
  if (MODE) {
#pragma unroll
    for (int e = 0; e < 8; ++e) { sc8[e] = ssc[l16 * 8 + e]; sh8[e] = ssh[l16 * 8 + e]; }
  }

  // ---- phase A: gather msg rows -> LDS ----
  {
    const uint4* hu = (const uint4*)h;  // h row = 16 uint4
#pragma unroll
    for (int p = 0; p < 8; ++p) {
      int nl = p * 16 + wave * 4 + quad;  // local row 0..127
      int n = row0 + nl;
      uint rawc = (n < N) ? cnt[n] : 0u;
      uint deg = min(rawc, (uint)CAP);
      const uint* row = csr + (size_t)n * CAP;
      float a0 = 0.f, a1 = 0.f, a2 = 0.f, a3 = 0.f, a4 = 0.f, a5 = 0.f, a6 = 0.f, a7 = 0.f;
      for (uint k = 0; k < deg; k += 8) {
        uint4 r0 = *(const uint4*)(row + k);      // rows are 128B, k mult of 8 -> aligned
        uint4 r1 = *(const uint4*)(row + k + 4);
        uint raw[8] = {r0.x, r0.y, r0.z, r0.w, r1.x, r1.y, r1.z, r1.w};
        uint idx[8];
        float msk[8];
#pragma unroll
        for (int j = 0; j < 8; ++j) {
          bool in = (k + j < deg);
          idx[j] = in ? raw[j] : (uint)N;  // N = zero row (safe address)
          msk[j] = in ? 1.f : 0.f;
        }
        uint4 v[8];
#pragma unroll
        for (int j = 0; j < 8; ++j) v[j] = hu[(size_t)idx[j] * 16 + l16];
#pragma unroll
        for (int j = 0; j < 8; ++j) {
          if (MODE) {  // on-the-fly prev-layer relu(bn(x)), masked accumulate
            a0 = fmaf(nrm(bflo(v[j].x), sc8[0], sh8[0]), msk[j], a0);
            a1 = fmaf(nrm(bfhi(v[j].x), sc8[1], sh8[1]), msk[j], a1);
            a2 = fmaf(nrm(bflo(v[j].y), sc8[2], sh8[2]), msk[j], a2);
            a3 = fmaf(nrm(bfhi(v[j].y), sc8[3], sh8[3]), msk[j], a3);
            a4 = fmaf(nrm(bflo(v[j].z), sc8[4], sh8[4]), msk[j], a4);
            a5 = fmaf(nrm(bfhi(v[j].z), sc8[5], sh8[5]), msk[j], a5);
            a6 = fmaf(nrm(bflo(v[j].w), sc8[6], sh8[6]), msk[j], a6);
            a7 = fmaf(nrm(bfhi(v[j].w), sc8[7], sh8[7]), msk[j], a7);
          } else {  // dummy rows are genuinely zero -> plain add
            a0 += bflo(v[j].x); a1 += bfhi(v[j].x);
            a2 += bflo(v[j].y); a3 += bfhi(v[j].y);
            a4 += bflo(v[j].z); a5 += bfhi(v[j].z);
            a6 += bflo(v[j].w); a7 += bfhi(v[j].w);
          }
        }
      }
      float inv = 1.0f / (float)max(rawc, 1u);
      uint4 o;
      o.x = (uint)f2bf(a0 * inv) | ((uint)f2bf(a1 * inv) << 16);
      o.y = (uint)f2bf(a2 * inv) | ((uint)f2bf(a3 * inv) << 16);
      o.z = (uint)f2bf(a4 * inv) | ((uint)f2bf(a5 * inv) << 16);
      o.w = (uint)f2bf(a6 * inv) | ((uint)f2bf(a7 * inv) << 16);
      int off = nl * 256 + ((l16 * 16) ^ ((nl & 7) << 4));  // swizzled 16B slot
      *(uint4*)((char*)sMsg + off) = o;
    }
  }

  // ---- phase B: MFMA ----
  int wrow0 = row0 + wave * 32;
  f32x4 acc[2][8];
#pragma unroll
  for (int m = 0; m < 2; ++m)
#pragma unroll
    for (int nt = 0; nt < 8; ++nt) acc[m][nt] = (f32x4){0.f, 0.f, 0.f, 0.f};
  short8 zf8 = {0, 0, 0, 0, 0, 0, 0, 0};
  const short8* Bp = (const short8*)Wsw;  // B-frags from L2: (kt*8+nt)*64+lane

  // self half (K 0..127, A = h from global, MODE: normalized on the fly)
#pragma unroll
  for (int kt = 0; kt < 4; ++kt) {
    int colb = kt * 32 + quad * 8;
    float scv[8], shv[8];
    if (MODE) {
#pragma unroll
      for (int e = 0; e < 8; ++e) { scv[e] = ssc[colb + e]; shv[e] = ssh[colb + e]; }
    }
    short8 a[2];
#pragma unroll
    for (int m = 0; m < 2; ++m) {
      int row = wrow0 + m * 16 + l16;
      if (row < N) {
        if (MODE) {
          uint4 vz = *(const uint4*)(h + (size_t)row * H + colb);
          ushort u[8];
          u[0] = f2bf(nrm(bflo(vz.x), scv[0], shv[0]));
          u[1] = f2bf(nrm(bfhi(vz.x), scv[1], shv[1]));
          u[2] = f2bf(nrm(bflo(vz.y), scv[2], shv[2]));
          u[3] = f2bf(nrm(bfhi(vz.y), scv[3], shv[3]));
          u[4] = f2bf(nrm(bflo(vz.z), scv[4], shv[4]));
          u[5] = f2bf(nrm(bfhi(vz.z), scv[5], shv[5]));
          u[6] = f2bf(nrm(bflo(vz.w), scv[6], shv[6]));
          u[7] = f2bf(nrm(bfhi(vz.w), scv[7], shv[7]));
          a[m] = *(short8*)u;
        } else {
          a[m] = *(const short8*)(h + (size_t)row * H + colb);
        }
      } else {
        a[m] = zf8;
      }
    }
#pragma unroll
    for (int nt = 0; nt < 8; ++nt) {
      short8 bfr = Bp[(kt * 8 + nt) * 64 + lane];
#pragma unroll
      for (int m = 0; m < 2; ++m)
        acc[m][nt] = __builtin_amdgcn_mfma_f32_16x16x32_bf16(a[m], bfr, acc[m][nt], 0, 0, 0);
    }
  }
  __syncthreads();  // msg tile complete
  // neighbor half (K 128..255, A = msg from LDS)
#pragma unroll
  for (int kt = 4; kt < 8; ++kt) {
    int cb = (kt - 4) * 64 + quad * 16;  // byte col base within row
    short8 a[2];
#pragma unroll
    for (int m = 0; m < 2; ++m) {
      int rl = wave * 32 + m * 16 + l16;  // rl&7 == l16&7
      a[m] = *(const short8*)((const char*)sMsg + rl * 256 + (cb ^ ((l16 & 7) << 4)));
    }
#pragma unroll
    for (int nt = 0; nt < 8; ++nt) {
      short8 bfr = Bp[(kt * 8 + nt) * 64 + lane];
#pragma unroll
      for (int m = 0; m < 2; ++m)
        acc[m][nt] = __builtin_amdgcn_mfma_f32_16x16x32_bf16(a[m], bfr, acc[m][nt], 0, 0, 0);
    }
  }

  // ---- epilogue: bias, z-write (bf16), fused BN partial sums ----
  float bs[8];
#pragma unroll
  for (int nt = 0; nt < 8; ++nt) bs[nt] = bias[nt * 16 + l16];
  float ps[8], pq[8];
#pragma unroll
  for (int nt = 0; nt < 8; ++nt) { ps[nt] = 0.f; pq[nt] = 0.f; }
#pragma unroll
  for (int m = 0; m < 2; ++m) {
#pragma unroll
    for (int nt = 0; nt < 8; ++nt) {
      int col = nt * 16 + l16;
#pragma unroll
      for (int r = 0; r < 4; ++r) {
        int row = wrow0 + m * 16 + quad * 4 + r;  // C/D: row=quad*4+reg
        if (row < N) {
          float v = acc[m][nt][r] + bs[nt];
          z[(size_t)row * H + col] = f2bf(v);
          ps[nt] += v; pq[nt] += v * v;
        }
      }
    }
  }
  __syncthreads();  // sMsg dead; alias reduction buffer over it (17.4KB < 32KB)
  float* red = (float*)sMsg;  // [16 wq][8 nt] stride 17 + l16 ; sumsq at +2176
  int wq = wave * 4 + quad;
#pragma unroll
  for (int nt = 0; nt < 8; ++nt) {
    red[(wq * 8 + nt) * 17 + l16] = ps[nt];
    red[2176 + (wq * 8 + nt) * 17 + l16] = pq[nt];
  }
  __syncthreads();
  if (tid < 128) {
    int nt = tid >> 4, lc = tid & 15;
    float s = 0.f, q = 0.f;
#pragma unroll
    for (int w2i = 0; w2i < 16; ++w2i) {
      s += red[(w2i * 8 + nt) * 17 + lc];
      q += red[2176 + (w2i * 8 + nt) * 17 + lc];
    }
    float* bank = bn_acc + (size_t)(blockIdx.x & (NB - 1)) * 256;
    atomicAdd(&bank[tid], s);
    atomicAdd(&bank[128 + tid], q);
  }
}

// h2 = relu(bn1(z1)) + relu(bn0(z0)), bf16, written IN PLACE over z0 (zh).
// Both BN finalizes inlined (sum NB banks each). n4 = N*16 uint4 elements.
__global__ __launch_bounds__(256) void k_norm2(const uint4* __restrict__ z1, uint4* __restrict__ zh,
                                               const float* __restrict__ bn1, const float* __restrict__ g1v,
                                               const float* __restrict__ b1v,
                                               const float* __restrict__ bn0, const float* __restrict__ g0v,
                                               const float* __restrict__ b0v,
                                               int n4, float invN) {
  __shared__ float s1c[128], s1h[128], s0c[128], s0h[128];
  int t = threadIdx.x;
  if (t < 128) {
    float s = 0.f, q = 0.f;
#pragma unroll
    for (int b = 0; b < NB; ++b) { s += bn1[b * 256 + t]; q += bn1[b * 256 + 128 + t]; }
    float mu = s * invN;
    float var = fmaxf(q * invN - mu * mu, 0.f);
    float sc = g1v[t] * rsqrtf(var + EPS);
    s1c[t] = sc; s1h[t] = b1v[t] - mu * sc;
    s = 0.f; q = 0.f;
#pragma unroll
    for (int b = 0; b < NB; ++b) { s += bn0[b * 256 + t]; q += bn0[b * 256 + 128 + t]; }
    mu = s * invN;
    var = fmaxf(q * invN - mu * mu, 0.f);
    sc = g0v[t] * rsqrtf(var + EPS);
    s0c[t] = sc; s0h[t] = b0v[t] - mu * sc;
  }
  __syncthreads();
  int idx = blockIdx.x * 256 + t;
  if (idx >= n4) return;
  int j = (idx & 15) * 8;  // cols j..j+7
  uint4 v = z1[idx];
  uint4 r = zh[idx];  // z0
  float x0 = nrm(bflo(v.x), s1c[j + 0], s1h[j + 0]) + nrm(bflo(r.x), s0c[j + 0], s0h[j + 0]);
  float x1 = nrm(bfhi(v.x), s1c[j + 1], s1h[j + 1]) + nrm(bfhi(r.x), s0c[j + 1], s0h[j + 1]);
  float x2 = nrm(bflo(v.y), s1c[j + 2], s1h[j + 2]) + nrm(bflo(r.y), s0c[j + 2], s0h[j + 2]);
  float x3 = nrm(bfhi(v.y), s1c[j + 3], s1h[j + 3]) + nrm(bfhi(r.y), s0c[j + 3], s0h[j + 3]);
  float x4 = nrm(bflo(v.z), s1c[j + 4], s1h[j + 4]) + nrm(bflo(r.z), s0c[j + 4], s0h[j + 4]);
  float x5 = nrm(bfhi(v.z), s1c[j + 5], s1h[j + 5]) + nrm(bfhi(r.z), s0c[j + 5], s0h[j + 5]);
  float x6 = nrm(bflo(v.w), s1c[j + 6], s1h[j + 6]) + nrm(bflo(r.w), s0c[j + 6], s0h[j + 6]);
  float x7 = nrm(bfhi(v.w), s1c[j + 7], s1h[j + 7]) + nrm(bfhi(r.w), s0c[j + 7], s0h[j + 7]);
  uint4 o;
  o.x = (uint)f2bf(x0) | ((uint)f2bf(x1) << 16);
  o.y = (uint)f2bf(x2) | ((uint)f2bf(x3) << 16);
  o.z = (uint)f2bf(x4) | ((uint)f2bf(x5) << 16);
  o.w = (uint)f2bf(x6) | ((uint)f2bf(x7) << 16);
  zh[idx] = o;
}

// Final layer: fused BN-normalize+relu+residual -> MLP head.
__global__ __launch_bounds__(256) void k_head(const ushort* __restrict__ z, const ushort* __restrict__ hprev,
                                              const float* __restrict__ bn_acc,
                                              const float* __restrict__ gamma,
                                              const float* __restrict__ beta, float invN,
                                              const ushort* __restrict__ W1sw,
                                              const float* __restrict__ b1, const float* __restrict__ W2,
                                              const float* __restrict__ b2, float* __restrict__ out, int N) {
  __shared__ float ssc[128], ssh[128];
  int tid = threadIdx.x;
  if (tid < 128) {
    float s = 0.f, q = 0.f;
#pragma unroll
    for (int b = 0; b < NB; ++b) {
      s += bn_acc[b * 256 + tid];
      q += bn_acc[b * 256 + 128 + tid];
    }
    float mu = s * invN;
    float var = fmaxf(q * invN - mu * mu, 0.f);
    float sc = gamma[tid] * rsqrtf(var + EPS);
    ssc[tid] = sc;
    ssh[tid] = beta[tid] - mu * sc;
  }
  __syncthreads();
  int wave = tid >> 6, lane = tid & 63, quad = lane >> 4, l16 = lane & 15;
  int wrow0 = blockIdx.x * 64 + wave * 16;
  int am = wrow0 + l16;
  bool avalid = am < N;
  short8 af[4];
#pragma unroll
  for (int kt = 0; kt < 4; ++kt) {
    int c0 = kt * 32 + quad * 8;
    uint4 vz = avalid ? ((const uint4*)z)[(size_t)am * 16 + kt * 4 + quad] : make_uint4(0, 0, 0, 0);
    uint4 vr = avalid ? ((const uint4*)hprev)[(size_t)am * 16 + kt * 4 + quad] : make_uint4(0, 0, 0, 0);
    float x0 = nrm(bflo(vz.x), ssc[c0 + 0], ssh[c0 + 0]) + bflo(vr.x);
    float x1 = nrm(bfhi(vz.x), ssc[c0 + 1], ssh[c0 + 1]) + bfhi(vr.x);
    float x2 = nrm(bflo(vz.y), ssc[c0 + 2], ssh[c0 + 2]) + bflo(vr.y);
    float x3 = nrm(bfhi(vz.y), ssc[c0 + 3], ssh[c0 + 3]) + bfhi(vr.y);
    float x4 = nrm(bflo(vz.z), ssc[c0 + 4], ssh[c0 + 4]) + bflo(vr.z);
    float x5 = nrm(bfhi(vz.z), ssc[c0 + 5], ssh[c0 + 5]) + bfhi(vr.z);
    float x6 = nrm(bflo(vz.w), ssc[c0 + 6], ssh[c0 + 6]) + bflo(vr.w);
    float x7 = nrm(bfhi(vz.w), ssc[c0 + 7], ssh[c0 + 7]) + bfhi(vr.w);
    ushort u[8] = {f2bf(x0), f2bf(x1), f2bf(x2), f2bf(x3), f2bf(x4), f2bf(x5), f2bf(x6), f2bf(x7)};
    af[kt] = *(short8*)u;
  }
  const short8* Bp = (const short8*)W1sw;
  f32x4 acc[4];
#pragma unroll
  for (int nt = 0; nt < 4; ++nt) acc[nt] = (f32x4){0.f, 0.f, 0.f, 0.f};
#pragma unroll
  for (int kt = 0; kt < 4; ++kt) {
#pragma unroll
    for (int nt = 0; nt < 4; ++nt) {
      short8 bfr = Bp[(kt * 4 + nt) * 64 + lane];
      acc[nt] = __builtin_amdgcn_mfma_f32_16x16x32_bf16(af[kt], bfr, acc[nt], 0, 0, 0);
    }
  }
  float p0[4] = {0.f, 0.f, 0.f, 0.f}, p1[4] = {0.f, 0.f, 0.f, 0.f};
#pragma unroll
  for (int nt = 0; nt < 4; ++nt) {
    int c = nt * 16 + l16;
    float bc = b1[c], w20 = W2[c * 2], w21 = W2[c * 2 + 1];
#pragma unroll
    for (int r = 0; r < 4; ++r) {
      float v = fmaxf(acc[nt][r] + bc, 0.f);
      p0[r] = fmaf(v, w20, p0[r]);
      p1[r] = fmaf(v, w21, p1[r]);
    }
  }
#pragma unroll
  for (int m = 1; m < 16; m <<= 1) {
#pragma unroll
    for (int r = 0; r < 4; ++r) {
      p0[r] += __shfl_xor(p0[r], m);
      p1[r] += __shfl_xor(p1[r], m);
    }
  }
  if (l16 == 0) {
    float b20 = b2[0], b21 = b2[1];
#pragma unroll
    for (int r = 0; r < 4; ++r) {
      int row = wrow0 + quad * 4 + r;
      if (row < N) {
        float2 o = make_float2(p0[r] + b20, p1[r] + b21);
        *(float2*)(out + (size_t)row * 2) = o;
      }
    }
  }
}

extern "C" void kernel_launch(void* const* d_in, const int* in_sizes, int n_in,
                              void* d_out, int out_size, void* d_ws, size_t ws_size,
                              hipStream_t stream) {
  const float* features = (const float*)d_in[0];
  const void*  edges    = d_in[1];
  const float* emb_W    = (const float*)d_in[2];
  const float* emb_b    = (const float*)d_in[3];
  const float* Wself    = (const float*)d_in[4];
  const float* Wneigh   = (const float*)d_in[5];
  const float* conv_b   = (const float*)d_in[6];
  const float* bn_gamma = (const float*)d_in[7];
  const float* bn_beta  = (const float*)d_in[8];
  const float* W1       = (const float*)d_in[9];
  const float* b1       = (const float*)d_in[10];
  const float* W2       = (const float*)d_in[11];
  const float* b2       = (const float*)d_in[12];
  float* out = (float*)d_out;
  const int N = in_sizes[0] / 12;
  const int E = in_sizes[1] / 2;
  const float invN = 1.0f / (float)N;

  char* ws = (char*)d_ws;
  size_t off = 0;
  auto take = [&](size_t bytes) {
    char* p = ws + off;
    off = (off + bytes + 511) & ~(size_t)511;
    return p;
  };
  int*    flag   = (int*)take(4);
  uint*   cnt    = (uint*)take((size_t)N * 4);
  uint*   csr    = (uint*)take((size_t)N * CAP * 4);  // bucket CSR (12.8 MB)
  float*  bn_all = (float*)take(NB * 256 * 3 * 4);    // per-layer banked BN accum
  ushort* Wsw    = (ushort*)take(3 * 4096 * 8 * 2);
  ushort* W1sw   = (ushort*)take(1024 * 8 * 2);
  ushort* bufA   = (ushort*)take(((size_t)N + 1) * H * 2);  // +1 zero row
  ushort* bufB   = (ushort*)take(((size_t)N + 1) * H * 2);

  const int ZB = (N + 255) / 256;                   // zero-cnt blocks
  const int EB = (N + 255) / 256;                   // embed blocks
  const int PB = (3 * 4096 + 1024 + 255) / 256;     // prepw blocks (52)
  const int FB = (E + 511) / 512;                   // fill blocks (2 edges/thread)
  const int GB = (N + 127) / 128;                   // fused gather+gemm blocks (M-tile 128)

  k_init<<<ZB + EB + PB, 256, 0, stream>>>(edges, N, cnt, flag, features, emb_W, emb_b,
                                           bufA, bufB, Wself, Wneigh, W1, Wsw, W1sw, bn_all, ZB, EB);
  k_fill<<<FB, 256, 0, stream>>>(edges, cnt, csr, E, flag);

  float* bn0 = bn_all;
  float* bn1 = bn_all + (size_t)NB * 256;
  float* bn2 = bn_all + (size_t)2 * NB * 256;
  const int n4 = N * 16;

  // L0: h0(bufA) -> z0(bufB)
  k_gg<0><<<GB, 256, 0, stream>>>(bufA, bufB, cnt, csr, Wsw, conv_b, bn0, N,
                                  nullptr, nullptr, nullptr, invN);
  // L1: reads z0(bufB) with on-the-fly h1 = relu(bn0(z0)); -> z1(bufA).
  // (k_norm for layer 0 is eliminated; h1 never materialized.)
  k_gg<1><<<GB, 256, 0, stream>>>(bufB, bufA, cnt, csr, Wsw + (size_t)4096 * 8, conv_b + H, bn1, N,
                                  bn0, bn_gamma, bn_beta, invN);
  // h2 = relu(bn1(z1)) + relu(bn0(z0)), in place over z0 (bufB)
  k_norm2<<<(n4 + 255) / 256, 256, 0, stream>>>((const uint4*)bufA, (uint4*)bufB,
                                                bn1, bn_gamma + H, bn_beta + H,
                                                bn0, bn_gamma, bn_beta, n4, invN);
  // L2: h2(bufB) -> z2(bufA)
  k_gg<0><<<GB, 256, 0, stream>>>(bufB, bufA, cnt, csr, Wsw + (size_t)2 * 4096 * 8, conv_b + 2 * H,
                                  bn2, N, nullptr, nullptr, nullptr, invN);
  // head: z2(bufA) + hprev=h2(bufB)
  k_head<<<(N + 63) / 64, 256, 0, stream>>>(bufA, bufB, bn2, bn_gamma + 2 * H, bn_beta + 2 * H,
                                            invN, W1sw, b1, W2, b2, out, N);
}